// Round 17
// baseline (505.362 us; speedup 1.0000x reference)
//
#include <hip/hip_runtime.h>
#include <hip/hip_bf16.h>

typedef __attribute__((ext_vector_type(8))) short bf16x8;   // 8 bf16 in 4 VGPRs
typedef __attribute__((ext_vector_type(4))) float f32x4;    // MFMA accumulator
typedef __attribute__((ext_vector_type(4))) int   i32x4;

#define NB 256
#define NT 200
#define NW 200
#define NE 768
#define NH 256
#define NEMB 32
#define KIN 800           // E + EMB
#define G3H 768           // 3*H
#define MROWS 51200       // B*T

__device__ __forceinline__ float bf2f(unsigned short h) {
    return __uint_as_float(((unsigned)h) << 16);
}
__device__ __forceinline__ unsigned short f2bf(float f) {
    unsigned u = __float_as_uint(f);
    u += 0x7fff + ((u >> 16) & 1);   // RNE
    return (unsigned short)(u >> 16);
}
__device__ __forceinline__ float sigm(float x) { return 1.0f / (1.0f + __expf(-x)); }
__device__ __forceinline__ float tanh_fast(float x) {
    float e = __expf(2.0f * x);
    return 1.0f - 2.0f / (e + 1.0f);
}

// async global->LDS, 16 B/lane. LDS dest: wave-uniform base + lane*16.
__device__ __forceinline__ void gload16(const void* g, void* l) {
    __builtin_amdgcn_global_load_lds((const __attribute__((address_space(1))) unsigned int*)g,
                                     (__attribute__((address_space(3))) unsigned int*)l,
                                     16, 0, 0);
}

// ---------------------------------------------------------------------------
// prep1 (shrunk): W_ih -> bf16 [768][800], W_out -> bf16 TRANSPOSED [256][768],
// biasC[768] = b_ih + (row<512 ? b_hh : 0). The A-build (240 MB of traffic)
// is fused into gemmX_f32 — this kernel is now ~4 MB total.
// ---------------------------------------------------------------------------
__global__ void prep1(const float* __restrict__ Wih, const float* __restrict__ Wout,
                      const float* __restrict__ bih, const float* __restrict__ bhh,
                      unsigned short* __restrict__ Wihbf,
                      unsigned short* __restrict__ WoutTbf, float* __restrict__ biasC) {
    const long gid0 = (long)blockIdx.x * blockDim.x + threadIdx.x;
    if (gid0 < G3H) biasC[gid0] = bih[gid0] + (gid0 < 512 ? bhh[gid0] : 0.0f);
    const long NWU = 768L << 7;          // 128 slots/row, 100 active
    const long NOU = 256L << 7;          // 128 slots/row, 96 active
    const long total = NWU + NOU;
    for (long u = gid0; u < total; u += (long)gridDim.x * blockDim.x) {
        bf16x8 v;
        unsigned short* dst;
        if (u < NWU) {
            const long row = u >> 7;
            const int c = (int)(u & 127);
            if (c >= 100) continue;
            const int c8 = c << 3;
            const float* s = Wih + row * KIN + c8;
            #pragma unroll
            for (int j = 0; j < 8; j++) v[j] = (short)f2bf(s[j]);
            dst = Wihbf + row * KIN + c8;
        } else {
            const long u3 = u - NWU;
            const long row = u3 >> 7;            // h index 0..255
            const int c = (int)(u3 & 127);
            if (c >= 96) continue;
            const int c8 = c << 3;               // e chunk
            #pragma unroll
            for (int j = 0; j < 8; j++)
                v[j] = (short)f2bf(Wout[(long)(c8 + j) * NH + row]);   // transpose gather
            dst = WoutTbf + row * NE + c8;
        }
        *(bf16x8*)dst = v;
    }
}

// ---------------------------------------------------------------------------
// gemmX_f32: xg[51200][768] = Araw @ Wih^T + biasC, where Araw[row][k] =
//   k<768 ? inputs[row][k] : emb[fix[row]][k-768]   (fp32, built on the fly).
// Fuses prep1's A-build (saves 82 MB write + 82 MB read + the separate
// inputs pass). A reg-staged fp32 -> bf16 RNE (bit-identical to prep1's
// conversion); B (Wihbf) via gload16. BM=128, BN=256 (3 N-blocks; A fp32
// re-reads L3-served — inputs 157 MB < 256 MB L3). K=800 = 25 tiles; tile 24
// is the emb gather. 512 threads (8 waves = 2Mx4N of 64x64). XCD swizzle
// with N-major tile order so consecutive blocks share the A panel.
// ---------------------------------------------------------------------------
__global__ __launch_bounds__(512)
void gemmX_f32(const float* __restrict__ inputs,        // [51200][768] fp32
               const int* __restrict__ fix_seq,          // [51200]
               const float* __restrict__ emb,            // [201][32] fp32
               const unsigned short* __restrict__ Bw,    // Wihbf [768][800] bf16
               const float* __restrict__ bias,           // biasC [768]
               unsigned short* __restrict__ Out) {       // xg [51200][768] bf16
    __shared__ unsigned short As[128 * 32];   //  8 KB
    __shared__ unsigned short Bs[256 * 32];   // 16 KB
    const int bid = (int)((blockIdx.x & 7) * (gridDim.x >> 3) + (blockIdx.x >> 3));
    const int m0 = (bid / 3) << 7;
    const int n0 = (bid % 3) << 8;
    const int tid = threadIdx.x;
    const int lane = tid & 63;
    const int wave = tid >> 6;
    const int wm = (wave >> 2) << 6;     // 0 / 64
    const int wn = (wave & 3) << 6;      // 0 / 64 / 128 / 192

    // A reg-staging: row = tid>>2 (0..127), k-quarter kq = tid&3 (8 floats)
    const int arow = tid >> 2;
    const int akq = tid & 3;
    const float* aptr = inputs + (long)(m0 + arow) * NE + akq * 8;
    const int fix = fix_seq[m0 + arow];
    const float* eptr = emb + (long)fix * NEMB + akq * 8;   // K-tile 24 source
    char* la = (char*)As + arow * 64 + akq * 16;

    // B staging (gload16, 2 rounds): thread -> row tid>>2 (+128), seg tid&3
    const int sseg = (tid & 3) << 4;
    const char* gBa = (const char*)(Bw + (long)(n0 + arow) * KIN) + sseg;
    const char* gBb = (const char*)(Bw + (long)(n0 + 128 + arow) * KIN) + sseg;
    char* lBa = (char*)Bs + wave * 1024;
    char* lBb = (char*)Bs + 8192 + wave * 1024;

    float4 fa0 = *(const float4*)(aptr);
    float4 fa1 = *(const float4*)(aptr + 4);

    f32x4 acc[4][4] = {};

    for (int kt = 0; kt < 25; kt++) {    // K = 800
        __syncthreads();                 // previous tile's LDS reads complete
        gload16(gBa + kt * 64, lBa);
        gload16(gBb + kt * 64, lBb);
        bf16x8 v;                        // convert + write A slice (RNE, = prep1)
        v[0] = (short)f2bf(fa0.x); v[1] = (short)f2bf(fa0.y);
        v[2] = (short)f2bf(fa0.z); v[3] = (short)f2bf(fa0.w);
        v[4] = (short)f2bf(fa1.x); v[5] = (short)f2bf(fa1.y);
        v[6] = (short)f2bf(fa1.z); v[7] = (short)f2bf(fa1.w);
        *(bf16x8*)la = v;
        asm volatile("s_waitcnt vmcnt(0)" ::: "memory");   // B landed
        __syncthreads();                 // all stages visible (incl. ds_writes)
        if (kt + 1 < 25) {               // A prefetch hides under MFMA phase
            const float* ap = (kt + 1 < 24) ? (aptr + (kt + 1) * 32) : eptr;
            fa0 = *(const float4*)(ap);
            fa1 = *(const float4*)(ap + 4);
        }
        bf16x8 af[4], bfr[4];
        #pragma unroll
        for (int mi = 0; mi < 4; mi++)
            af[mi] = *(const bf16x8*)((const char*)As +
                        (wm + mi * 16 + (lane & 15)) * 64 + ((lane >> 4) << 4));
        #pragma unroll
        for (int ni = 0; ni < 4; ni++)
            bfr[ni] = *(const bf16x8*)((const char*)Bs +
                        (wn + ni * 16 + (lane & 15)) * 64 + ((lane >> 4) << 4));
        #pragma unroll
        for (int mi = 0; mi < 4; mi++)
            #pragma unroll
            for (int ni = 0; ni < 4; ni++)
                acc[mi][ni] = __builtin_amdgcn_mfma_f32_16x16x32_bf16(
                                  af[mi], bfr[ni], acc[mi][ni], 0, 0, 0);
    }
    // epilogue: D col = lane&15, row = (lane>>4)*4 + r  (m89-verified layout)
    #pragma unroll
    for (int ni = 0; ni < 4; ni++) {
        const int col = n0 + wn + ni * 16 + (lane & 15);
        const float bv = bias[col];
        #pragma unroll
        for (int mi = 0; mi < 4; mi++) {
            const int row = m0 + wm + mi * 16 + ((lane >> 4) << 2);
            #pragma unroll
            for (int r = 0; r < 4; r++)
                Out[(long)(row + r) * G3H + col] = f2bf(acc[mi][ni][r] + bv);
        }
    }
}

// ---------------------------------------------------------------------------
// gemmG_f32: G[M][256] = fwe[M][768](fp32) @ WoutT[256][768](bf16)^T.
// BN = 256 (full N per block) -> fwe read exactly once. (R15 form, frozen.)
// ---------------------------------------------------------------------------
__global__ __launch_bounds__(512)
void gemmG_f32(const float* __restrict__ fwe,           // [51200][768] fp32
               const unsigned short* __restrict__ BwT,  // WoutT [256][768] bf16
               const float* __restrict__ bout,          // [768]
               unsigned short* __restrict__ G,          // [51200][256] bf16
               unsigned char* __restrict__ wmask,       // [51200]
               float* __restrict__ dvec) {              // [51200]
    __shared__ unsigned short As[128 * 32];   //  8 KB
    __shared__ unsigned short Bs[256 * 32];   // 16 KB
    __shared__ float Bo[G3H];                 //  3 KB
    const int m0 = (int)blockIdx.x << 7;
    const int tid = threadIdx.x;
    const int lane = tid & 63;
    const int wave = tid >> 6;
    const int wm = (wave >> 2) << 6;     // 0 / 64
    const int wn = (wave & 3) << 6;      // 0 / 64 / 128 / 192

    const int arow = tid >> 2;
    const int akq = tid & 3;
    const float* aptr = fwe + (long)(m0 + arow) * NE + akq * 8;
    char* la = (char*)As + arow * 64 + akq * 16;

    const int sseg = (tid & 3) << 4;
    const char* gBa = (const char*)(BwT + (long)arow * NE) + sseg;          // rows 0-127
    const char* gBb = (const char*)(BwT + (long)(128 + arow) * NE) + sseg;  // rows 128-255
    char* lBa = (char*)Bs + wave * 1024;
    char* lBb = (char*)Bs + 8192 + wave * 1024;

    for (int i = tid; i < G3H; i += 512) Bo[i] = bout[i];

    float4 fa0 = *(const float4*)(aptr);
    float4 fa1 = *(const float4*)(aptr + 4);

    f32x4 acc[4][4] = {};
    float asum = 0.0f, vdot = 0.0f;

    __syncthreads();                     // Bo visible

    for (int kt = 0; kt < 24; kt++) {    // K = 768
        __syncthreads();                 // previous tile's LDS reads complete
        gload16(gBa + kt * 64, lBa);
        gload16(gBb + kt * 64, lBb);
        const float* bo = Bo + kt * 32 + akq * 8;
        const float4 b0 = *(const float4*)(bo);
        const float4 b1 = *(const float4*)(bo + 4);
        asum += fabsf(fa0.x) + fabsf(fa0.y) + fabsf(fa0.z) + fabsf(fa0.w)
              + fabsf(fa1.x) + fabsf(fa1.y) + fabsf(fa1.z) + fabsf(fa1.w);
        vdot += fa0.x * b0.x + fa0.y * b0.y + fa0.z * b0.z + fa0.w * b0.w
              + fa1.x * b1.x + fa1.y * b1.y + fa1.z * b1.z + fa1.w * b1.w;
        bf16x8 v;
        v[0] = (short)f2bf(fa0.x); v[1] = (short)f2bf(fa0.y);
        v[2] = (short)f2bf(fa0.z); v[3] = (short)f2bf(fa0.w);
        v[4] = (short)f2bf(fa1.x); v[5] = (short)f2bf(fa1.y);
        v[6] = (short)f2bf(fa1.z); v[7] = (short)f2bf(fa1.w);
        *(bf16x8*)la = v;
        asm volatile("s_waitcnt vmcnt(0)" ::: "memory");   // B landed
        __syncthreads();                 // all stages visible (incl. ds_writes)
        if (kt + 1 < 24) {               // A prefetch hides under MFMA phase
            const float* ap = aptr + (kt + 1) * 32;
            fa0 = *(const float4*)(ap);
            fa1 = *(const float4*)(ap + 4);
        }
        bf16x8 af[4], bfr[4];
        #pragma unroll
        for (int mi = 0; mi < 4; mi++)
            af[mi] = *(const bf16x8*)((const char*)As +
                        (wm + mi * 16 + (lane & 15)) * 64 + ((lane >> 4) << 4));
        #pragma unroll
        for (int ni = 0; ni < 4; ni++)
            bfr[ni] = *(const bf16x8*)((const char*)Bs +
                        (wn + ni * 16 + (lane & 15)) * 64 + ((lane >> 4) << 4));
        #pragma unroll
        for (int mi = 0; mi < 4; mi++)
            #pragma unroll
            for (int ni = 0; ni < 4; ni++)
                acc[mi][ni] = __builtin_amdgcn_mfma_f32_16x16x32_bf16(
                                  af[mi], bfr[ni], acc[mi][ni], 0, 0, 0);
    }
    asum += __shfl_xor(asum, 1);  asum += __shfl_xor(asum, 2);
    vdot += __shfl_xor(vdot, 1);  vdot += __shfl_xor(vdot, 2);
    if (akq == 0) {
        wmask[m0 + arow] = (asum != 0.0f) ? 1 : 0;
        dvec[m0 + arow] = vdot;
    }
    #pragma unroll
    for (int ni = 0; ni < 4; ni++) {
        const int col = wn + ni * 16 + (lane & 15);
        #pragma unroll
        for (int mi = 0; mi < 4; mi++) {
            const int row = m0 + wm + mi * 16 + ((lane >> 4) << 2);
            #pragma unroll
            for (int r = 0; r < 4; r++)
                G[(long)(row + r) * NH + col] = f2bf(acc[mi][ni][r]);
        }
    }
}

// ---------------------------------------------------------------------------
// gru_scan: REVERT to the R6 i8-MFMA form (measured 232 us). R16 forensics:
// the dot4 "SDOT4" path issued ~790 VALU inst/wave/step = 96 x 8 — the
// builtin was lowered to the 8-op scalar expansion on gfx950, so the dot4
// rewrite (R7+) never beat this configuration. 256 blocks x 1024 threads
// (16 waves); wave owns 16 h-cols; wf = 48 VGPR i8 frags; K=64 i8 MFMA.
// ---------------------------------------------------------------------------
__global__ __launch_bounds__(1024)
__attribute__((amdgpu_waves_per_eu(4, 4)))
void gru_scan(const unsigned short* __restrict__ xg,   // [51200][768] bf16 (incl biasC)
              const float* __restrict__ Whh,            // [768][256] fp32
              const float* __restrict__ bhh,            // [768]
              const int* __restrict__ lengths,          // [256]
              unsigned short* __restrict__ hout) {      // [51200][256] bf16 (masked)
    __shared__ __align__(16) unsigned char h8[2][256];  // int8 h double buffer
    const int tid = threadIdx.x;
    const int lane = tid & 63;
    const int wave = tid >> 6;               // 0..15
    const int b = blockIdx.x;
    const int l = lane & 15;
    const int sub = lane >> 4;               // k-subslice 0..3
    const int c = wave * 16 + l;             // this lane's h-col

    // resident W_hh i8 B-frags: gate g, ktile kt: byte j <- W[g*256+c][kt*64+sub*16+j]
    i32x4 wf[3][4];
    #pragma unroll
    for (int g = 0; g < 3; g++) {
        const float* wr = Whh + (long)(g * 256 + c) * NH;
        #pragma unroll
        for (int kt = 0; kt < 4; kt++) {
            const float* s = wr + kt * 64 + sub * 16;
            i32x4 v;
            #pragma unroll
            for (int q = 0; q < 4; q++) {
                unsigned pack = 0;
                #pragma unroll
                for (int j = 0; j < 4; j++) {
                    int wq = (int)rintf(s[q * 4 + j] * 400.0f);
                    wq = wq > 127 ? 127 : (wq < -127 ? -127 : wq);
                    pack |= ((unsigned)(wq & 0xff)) << (8 * j);
                }
                v[q] = (int)pack;
            }
            wf[g][kt] = v;
        }
    }
    const float bhn = bhh[512 + c];          // n-gate b_hh (r,z folded into xg)
    const int len = lengths[b];
    if (tid < 128) ((unsigned*)h8)[tid] = 0u;   // zero both h buffers (512 B)

    const unsigned short* xrow = xg + (long)b * NT * G3H;
    const bool gl = (lane < 16);
    unsigned short xv0 = 0, xv1 = 0, xv2 = 0;
    if (gl) { xv0 = xrow[c]; xv1 = xrow[256 + c]; xv2 = xrow[512 + c]; }
    float hp = 0.0f;
    const float ISC = 1.0f / (400.0f * 127.0f);

    asm volatile("s_waitcnt lgkmcnt(0)" ::: "memory");
    __builtin_amdgcn_sched_barrier(0);
    __builtin_amdgcn_s_barrier();
    __builtin_amdgcn_sched_barrier(0);

    for (int t = 0; t < NT; t++) {
        // hg = h_{t-1} @ Whh^T for this wave's 16 cols x 3 gates (i8, K=64)
        const unsigned char* hb = h8[(t + 1) & 1];
        i32x4 a0 = {}, a1 = {}, a2 = {};
        #pragma unroll
        for (int kt = 0; kt < 4; kt++) {
            const i32x4 af = *(const i32x4*)(hb + kt * 64 + (sub << 4));
            a0 = __builtin_amdgcn_mfma_i32_16x16x64_i8(af, wf[0][kt], a0, 0, 0, 0);
            a1 = __builtin_amdgcn_mfma_i32_16x16x64_i8(af, wf[1][kt], a1, 0, 0, 0);
            a2 = __builtin_amdgcn_mfma_i32_16x16x64_i8(af, wf[2][kt], a2, 0, 0, 0);
        }
        if (gl) {
            const float r = sigm(bf2f(xv0) + (float)a0[0] * ISC);
            const float z = sigm(bf2f(xv1) + (float)a1[0] * ISC);
            const float n = tanh_fast(bf2f(xv2) + r * ((float)a2[0] * ISC + bhn));
            hp = (1.0f - z) * n + z * hp;
            h8[t & 1][c] = (unsigned char)((int)rintf(hp * 127.0f) & 0xff);
            hout[((long)b * NT + t) * NH + c] = (t < len) ? f2bf(hp) : (unsigned short)0;
            if (t + 1 < NT) {                 // prefetch next step's xg (floats past barrier)
                const unsigned short* xn = xrow + (long)(t + 1) * G3H;
                xv0 = xn[c]; xv1 = xn[256 + c]; xv2 = xn[512 + c];
            }
        }
        // LDS-only baton: no vmcnt drain (hout stores + xg prefetch stay in flight)
        asm volatile("s_waitcnt lgkmcnt(0)" ::: "memory");
        __builtin_amdgcn_sched_barrier(0);
        __builtin_amdgcn_s_barrier();
        __builtin_amdgcn_sched_barrier(0);
    }
}

// ---------------------------------------------------------------------------
// logits_dur: wave per (b,t) row; only |w-fix|<=8 dots computed; dur fused.
// (R11 form, unchanged.)
// ---------------------------------------------------------------------------
__global__ __launch_bounds__(256)
void logits_dur(const unsigned short* __restrict__ Hrow,   // hout [51200][256]
                const unsigned short* __restrict__ G,      // [51200][256]
                const int* __restrict__ fix_seq,           // [51200]
                const unsigned char* __restrict__ wmask,   // [51200]
                const float* __restrict__ dvec,            // [51200]
                const float* __restrict__ Wdur, const float* __restrict__ bdur,
                float* __restrict__ out) {
    __shared__ float dots[4][20];
    const int wv = threadIdx.x >> 6;
    const int gwave = (int)blockIdx.x * 4 + wv;            // 0..51199 = b*200+t
    const int lane = threadIdx.x & 63;
    const int l16 = lane & 15;
    const int grp = lane >> 4;                              // 0..3
    const int b = gwave / NT;

    const unsigned short* hp = Hrow + (long)gwave * NH + l16 * 16;
    const bf16x8 h0 = *(const bf16x8*)hp;
    const bf16x8 h1 = *(const bf16x8*)(hp + 8);
    float hf[16];
    #pragma unroll
    for (int j = 0; j < 8; j++) { hf[j] = bf2f((unsigned short)h0[j]);
                                  hf[8 + j] = bf2f((unsigned short)h1[j]); }

    const int fix = fix_seq[gwave];
    const int wbase = fix - 8;

    if (fix != 0) {
        #pragma unroll
        for (int it = 0; it < 5; it++) {
            const int wi = it * 4 + grp;                    // 0..19 (17..19 unused)
            int w = wbase + wi;
            w = w < 0 ? 0 : (w > NW - 1 ? NW - 1 : w);      // clamp for safe load
            const unsigned short* gp = G + ((long)b * NW + w) * NH + l16 * 16;
            const bf16x8 g0 = *(const bf16x8*)gp;
            const bf16x8 g1 = *(const bf16x8*)(gp + 8);
            float p = 0.0f;
            #pragma unroll
            for (int j = 0; j < 8; j++) {
                p += hf[j] * bf2f((unsigned short)g0[j]);
                p += hf[8 + j] * bf2f((unsigned short)g1[j]);
            }
            p += __shfl_xor(p, 1); p += __shfl_xor(p, 2);
            p += __shfl_xor(p, 4); p += __shfl_xor(p, 8);
            if (l16 == 0 && wi < 17) dots[wv][wi] = p;
        }
    }
    float pd = 0.0f;
    #pragma unroll
    for (int j = 0; j < 16; j++) pd += hf[j] * Wdur[l16 * 16 + j];
    pd += __shfl_xor(pd, 1); pd += __shfl_xor(pd, 2);
    pd += __shfl_xor(pd, 4); pd += __shfl_xor(pd, 8);
    if (lane == 0) out[(long)NB * NT * NW + gwave] = pd + bdur[0];

    __syncthreads();

    if (lane < 50) {
        float4 o;
        #pragma unroll
        for (int c = 0; c < 4; c++) {
            const int w = lane * 4 + c;
            const int wi = w - wbase;
            const int wic = wi < 0 ? 0 : (wi > 16 ? 16 : wi);
            const bool ok = (fix != 0) && ((unsigned)wi < 17u) && (wmask[b * NW + w] != 0);
            const float val = dots[wv][wic] + dvec[b * NW + w];
            ((float*)&o)[c] = ok ? val : -1e9f;
        }
        *(float4*)(out + (long)gwave * NW + lane * 4) = o;
    }
}

// ---------------------------------------------------------------------------
extern "C" void kernel_launch(void* const* d_in, const int* in_sizes, int n_in,
                              void* d_out, int out_size, void* d_ws, size_t ws_size,
                              hipStream_t stream) {
    (void)in_sizes; (void)n_in; (void)out_size; (void)ws_size;
    const float* inputs  = (const float*)d_in[0];
    const int*   fix_seq = (const int*)d_in[1];
    const float* fwe     = (const float*)d_in[2];
    const int*   lengths = (const int*)d_in[3];
    const float* emb     = (const float*)d_in[5];
    const float* Wih     = (const float*)d_in[6];
    const float* bih     = (const float*)d_in[7];
    const float* Whh     = (const float*)d_in[8];
    const float* bhh     = (const float*)d_in[9];
    const float* Wout    = (const float*)d_in[10];
    const float* bout    = (const float*)d_in[11];
    const float* Wdur    = (const float*)d_in[12];
    const float* bdur    = (const float*)d_in[13];
    float* out = (float*)d_out;

    char* ws = (char*)d_ws;
    // region layout (bytes, all 256-aligned):
    //   R0 [0, 81,920,000)            G bf16 [51200][256] (Abf eliminated)
    //   R1 [81,920,000, +78,643,200)  xg_bf16 [51200][768]
    //   R2 [160,563,200, +26,214,400) hout_bf16 [51200][256]
    //   [186,777,600, +1,228,800)     W_ih bf16
    //   [188,006,400, +393,216)       W_outT bf16 [256][768]
    //   [188,399,616, +51,200)        word_mask u8
    //   [188,450,816, +3,072)         biasC f32 [768]
    //   [188,453,888, +204,800)       dvec f32 [51200]
    unsigned short* Gbf     = (unsigned short*)(ws);
    unsigned short* xgbf    = (unsigned short*)(ws + 81920000);
    unsigned short* hout    = (unsigned short*)(ws + 160563200);
    unsigned short* Wihbf   = (unsigned short*)(ws + 186777600);
    unsigned short* WoutTbf = (unsigned short*)(ws + 188006400);
    unsigned char*  wmask   = (unsigned char*)(ws + 188399616);
    float*          biasC   = (float*)(ws + 188450816);
    float*          dvec    = (float*)(ws + 188453888);

    prep1<<<512, 256, 0, stream>>>(Wih, Wout, bih, bhh, Wihbf, WoutTbf, biasC);
    gemmX_f32<<<400 * 3, 512, 0, stream>>>(inputs, fix_seq, emb, Wihbf, biasC, xgbf);
    gemmG_f32<<<400, 512, 0, stream>>>(fwe, WoutTbf, bout, Gbf, wmask, dvec);
    gru_scan<<<256, 1024, 0, stream>>>(xgbf, Whh, bhh, lengths, hout);
    logits_dur<<<12800, 256, 0, stream>>>(hout, Gbf, fix_seq, wmask, dvec, Wdur, bdur, out);
}

// Round 18
// 452.315 us; speedup vs baseline: 1.1173x; 1.1173x over previous
//
#include <hip/hip_runtime.h>
#include <hip/hip_bf16.h>

typedef __attribute__((ext_vector_type(8))) short bf16x8;   // 8 bf16 in 4 VGPRs
typedef __attribute__((ext_vector_type(4))) float f32x4;    // MFMA accumulator
typedef __attribute__((ext_vector_type(4))) int   i32x4;

#define NB 256
#define NT 200
#define NW 200
#define NE 768
#define NH 256
#define NEMB 32
#define KIN 800           // E + EMB
#define G3H 768           // 3*H
#define MROWS 51200       // B*T

__device__ __forceinline__ float bf2f(unsigned short h) {
    return __uint_as_float(((unsigned)h) << 16);
}
__device__ __forceinline__ unsigned short f2bf(float f) {
    unsigned u = __float_as_uint(f);
    u += 0x7fff + ((u >> 16) & 1);   // RNE
    return (unsigned short)(u >> 16);
}
__device__ __forceinline__ float sigm(float x) { return 1.0f / (1.0f + __expf(-x)); }
__device__ __forceinline__ float tanh_fast(float x) {
    float e = __expf(2.0f * x);
    return 1.0f - 2.0f / (e + 1.0f);
}

// async global->LDS, 16 B/lane. LDS dest: wave-uniform base + lane*16.
__device__ __forceinline__ void gload16(const void* g, void* l) {
    __builtin_amdgcn_global_load_lds((const __attribute__((address_space(1))) unsigned int*)g,
                                     (__attribute__((address_space(3))) unsigned int*)l,
                                     16, 0, 0);
}

// ---------------------------------------------------------------------------
// prep1 (R16 form): A_bf16[51200][800] = [bf16(inputs) | bf16(emb[fix])],
// W_ih -> bf16 [768][800], W_out -> bf16 TRANSPOSED [256][768],
// biasC[768] = b_ih + (row<512 ? b_hh : 0). Div-free decomposition.
// (R17's gemmX fusion regressed +59 us: moved A traffic into the GEMM x3
// as fp32 instead of once as bf16 — reverted.)
// ---------------------------------------------------------------------------
__global__ void prep1(const float* __restrict__ inputs, const int* __restrict__ fix_seq,
                      const float* __restrict__ emb, const float* __restrict__ Wih,
                      const float* __restrict__ Wout, const float* __restrict__ bih,
                      const float* __restrict__ bhh,
                      unsigned short* __restrict__ Abf, unsigned short* __restrict__ Wihbf,
                      unsigned short* __restrict__ WoutTbf, float* __restrict__ biasC) {
    const long gid0 = (long)blockIdx.x * blockDim.x + threadIdx.x;
    if (gid0 < G3H) biasC[gid0] = bih[gid0] + (gid0 < 512 ? bhh[gid0] : 0.0f);
    const long NA = (long)MROWS << 7;    // 128 slots/row, 100 active
    const long NWU = 768L << 7;
    const long NOU = 256L << 7;          // 128 slots/row, 96 active
    const long total = NA + NWU + NOU;
    for (long u = gid0; u < total; u += (long)gridDim.x * blockDim.x) {
        bf16x8 v;
        unsigned short* dst;
        if (u < NA) {
            const long row = u >> 7;
            const int c = (int)(u & 127);
            if (c >= 100) continue;
            const int c8 = c << 3;
            const float* s;
            if (c8 < NE) {
                s = inputs + row * NE + c8;
            } else {
                int fx = fix_seq[row];
                s = emb + (long)fx * NEMB + (c8 - NE);
            }
            #pragma unroll
            for (int j = 0; j < 8; j++) v[j] = (short)f2bf(s[j]);
            dst = Abf + row * KIN + c8;
        } else if (u < NA + NWU) {
            const long u2 = u - NA;
            const long row = u2 >> 7;
            const int c = (int)(u2 & 127);
            if (c >= 100) continue;
            const int c8 = c << 3;
            const float* s = Wih + row * KIN + c8;
            #pragma unroll
            for (int j = 0; j < 8; j++) v[j] = (short)f2bf(s[j]);
            dst = Wihbf + row * KIN + c8;
        } else {
            const long u3 = u - NA - NWU;
            const long row = u3 >> 7;            // h index 0..255
            const int c = (int)(u3 & 127);
            if (c >= 96) continue;
            const int c8 = c << 3;               // e chunk
            #pragma unroll
            for (int j = 0; j < 8; j++)
                v[j] = (short)f2bf(Wout[(long)(c8 + j) * NH + row]);   // transpose gather
            dst = WoutTbf + row * NE + c8;
        }
        *(bf16x8*)dst = v;
    }
}

// ---------------------------------------------------------------------------
// gemm_bt128 (R16 form): Out[M][N] bf16 = A[M][K] * Bw[N][K]^T + bias.
// BM=128, BN=256, BK=32, 512 threads (8 waves = 2Mx4N of 64x64).
// T4 counted-vmcnt(3) pipeline, gload16, XCD-bijective swizzle.
// ---------------------------------------------------------------------------
__global__ __launch_bounds__(512, 4)
void gemm_bt128(const unsigned short* __restrict__ A,
                const unsigned short* __restrict__ Bw,
                const float* __restrict__ bias,
                unsigned short* __restrict__ Out,
                int M, int N, int K) {
    __shared__ unsigned short As[2][128 * 32];   // 2 x 8 KB
    __shared__ unsigned short Bs[2][256 * 32];   // 2 x 16 KB
    const int bid = (int)((blockIdx.x & 7) * (gridDim.x >> 3) + (blockIdx.x >> 3));
    const int nblk = N >> 8;
    const int m0 = (bid / nblk) << 7;
    const int n0 = (bid % nblk) << 8;
    const int tid = threadIdx.x;
    const int lane = tid & 63;
    const int wave = tid >> 6;
    const int wm = (wave >> 2) << 6;     // 0 / 64
    const int wn = (wave & 3) << 6;      // 0 / 64 / 128 / 192
    const int nk = K >> 5;

    const int srow = tid >> 2;           // 0..127
    const int sseg = (tid & 3) << 4;
    const char* gA  = (const char*)(A + (long)(m0 + srow) * K) + sseg;
    const char* gB0 = (const char*)(Bw + (long)(n0 + srow) * K) + sseg;
    const char* gB1 = (const char*)(Bw + (long)(n0 + 128 + srow) * K) + sseg;
    const int lofs = wave * 1024;        // 512 thr x 16 B = one 8 KB gload span

    f32x4 acc[4][4] = {};

    // prologue: stage tile 0 (3 loads in flight)
    gload16(gA,  (char*)As[0] + lofs);
    gload16(gB0, (char*)Bs[0] + lofs);
    gload16(gB1, (char*)Bs[0] + 8192 + lofs);

    int cur = 0;
    for (int kt = 0; kt < nk; kt++) {
        if (kt + 1 < nk) {               // stage NEXT tile; stays in flight past barrier
            gload16(gA  + (kt + 1) * 64, (char*)As[cur ^ 1] + lofs);
            gload16(gB0 + (kt + 1) * 64, (char*)Bs[cur ^ 1] + lofs);
            gload16(gB1 + (kt + 1) * 64, (char*)Bs[cur ^ 1] + 8192 + lofs);
            asm volatile("s_waitcnt vmcnt(3)" ::: "memory");   // oldest 3 (= buf[cur]) done
        } else {
            asm volatile("s_waitcnt vmcnt(0)" ::: "memory");   // last tile: drain
        }
        __builtin_amdgcn_sched_barrier(0);
        __builtin_amdgcn_s_barrier();      // all waves' buf[cur] stage-writes visible
        __builtin_amdgcn_sched_barrier(0);
        bf16x8 af[4], bfr[4];
        #pragma unroll
        for (int mi = 0; mi < 4; mi++)
            af[mi] = *(const bf16x8*)((const char*)As[cur] +
                        (wm + mi * 16 + (lane & 15)) * 64 + ((lane >> 4) << 4));
        #pragma unroll
        for (int ni = 0; ni < 4; ni++)
            bfr[ni] = *(const bf16x8*)((const char*)Bs[cur] +
                        (wn + ni * 16 + (lane & 15)) * 64 + ((lane >> 4) << 4));
        #pragma unroll
        for (int mi = 0; mi < 4; mi++)
            #pragma unroll
            for (int ni = 0; ni < 4; ni++)
                acc[mi][ni] = __builtin_amdgcn_mfma_f32_16x16x32_bf16(
                                  af[mi], bfr[ni], acc[mi][ni], 0, 0, 0);
        // WAR: this wave's ds_reads retired, then block-wide barrier before
        // buf[cur] is overwritten next iteration. No vmcnt drain here.
        asm volatile("s_waitcnt lgkmcnt(0)" ::: "memory");
        __builtin_amdgcn_sched_barrier(0);
        __builtin_amdgcn_s_barrier();
        __builtin_amdgcn_sched_barrier(0);
        cur ^= 1;
    }
    // epilogue: D col = lane&15, row = (lane>>4)*4 + r  (m89-verified layout)
    #pragma unroll
    for (int ni = 0; ni < 4; ni++) {
        const int col = n0 + wn + ni * 16 + (lane & 15);
        const float bv = bias[col];
        #pragma unroll
        for (int mi = 0; mi < 4; mi++) {
            const int row = m0 + wm + mi * 16 + ((lane >> 4) << 2);
            #pragma unroll
            for (int r = 0; r < 4; r++)
                Out[(long)(row + r) * N + col] = f2bf(acc[mi][ni][r] + bv);
        }
    }
}

// ---------------------------------------------------------------------------
// gemmG_f32 (R15 form): G[M][256] = fwe[M][768](fp32) @ WoutT[256][768]^T.
// BN = 256 (full N per block) -> fwe read exactly once; wmask/dvec folded.
// ---------------------------------------------------------------------------
__global__ __launch_bounds__(512)
void gemmG_f32(const float* __restrict__ fwe,           // [51200][768] fp32
               const unsigned short* __restrict__ BwT,  // WoutT [256][768] bf16
               const float* __restrict__ bout,          // [768]
               unsigned short* __restrict__ G,          // [51200][256] bf16
               unsigned char* __restrict__ wmask,       // [51200]
               float* __restrict__ dvec) {              // [51200]
    __shared__ unsigned short As[128 * 32];   //  8 KB
    __shared__ unsigned short Bs[256 * 32];   // 16 KB
    __shared__ float Bo[G3H];                 //  3 KB
    const int m0 = (int)blockIdx.x << 7;
    const int tid = threadIdx.x;
    const int lane = tid & 63;
    const int wave = tid >> 6;
    const int wm = (wave >> 2) << 6;     // 0 / 64
    const int wn = (wave & 3) << 6;      // 0 / 64 / 128 / 192

    const int arow = tid >> 2;
    const int akq = tid & 3;
    const float* aptr = fwe + (long)(m0 + arow) * NE + akq * 8;
    char* la = (char*)As + arow * 64 + akq * 16;

    const int sseg = (tid & 3) << 4;
    const char* gBa = (const char*)(BwT + (long)arow * NE) + sseg;          // rows 0-127
    const char* gBb = (const char*)(BwT + (long)(128 + arow) * NE) + sseg;  // rows 128-255
    char* lBa = (char*)Bs + wave * 1024;
    char* lBb = (char*)Bs + 8192 + wave * 1024;

    for (int i = tid; i < G3H; i += 512) Bo[i] = bout[i];

    float4 fa0 = *(const float4*)(aptr);
    float4 fa1 = *(const float4*)(aptr + 4);

    f32x4 acc[4][4] = {};
    float asum = 0.0f, vdot = 0.0f;

    __syncthreads();                     // Bo visible

    for (int kt = 0; kt < 24; kt++) {    // K = 768
        __syncthreads();                 // previous tile's LDS reads complete
        gload16(gBa + kt * 64, lBa);
        gload16(gBb + kt * 64, lBb);
        const float* bo = Bo + kt * 32 + akq * 8;
        const float4 b0 = *(const float4*)(bo);
        const float4 b1 = *(const float4*)(bo + 4);
        asum += fabsf(fa0.x) + fabsf(fa0.y) + fabsf(fa0.z) + fabsf(fa0.w)
              + fabsf(fa1.x) + fabsf(fa1.y) + fabsf(fa1.z) + fabsf(fa1.w);
        vdot += fa0.x * b0.x + fa0.y * b0.y + fa0.z * b0.z + fa0.w * b0.w
              + fa1.x * b1.x + fa1.y * b1.y + fa1.z * b1.z + fa1.w * b1.w;
        bf16x8 v;
        v[0] = (short)f2bf(fa0.x); v[1] = (short)f2bf(fa0.y);
        v[2] = (short)f2bf(fa0.z); v[3] = (short)f2bf(fa0.w);
        v[4] = (short)f2bf(fa1.x); v[5] = (short)f2bf(fa1.y);
        v[6] = (short)f2bf(fa1.z); v[7] = (short)f2bf(fa1.w);
        *(bf16x8*)la = v;
        asm volatile("s_waitcnt vmcnt(0)" ::: "memory");   // B landed
        __syncthreads();                 // all stages visible (incl. ds_writes)
        if (kt + 1 < 24) {               // A prefetch hides under MFMA phase
            const float* ap = aptr + (kt + 1) * 32;
            fa0 = *(const float4*)(ap);
            fa1 = *(const float4*)(ap + 4);
        }
        bf16x8 af[4], bfr[4];
        #pragma unroll
        for (int mi = 0; mi < 4; mi++)
            af[mi] = *(const bf16x8*)((const char*)As +
                        (wm + mi * 16 + (lane & 15)) * 64 + ((lane >> 4) << 4));
        #pragma unroll
        for (int ni = 0; ni < 4; ni++)
            bfr[ni] = *(const bf16x8*)((const char*)Bs +
                        (wn + ni * 16 + (lane & 15)) * 64 + ((lane >> 4) << 4));
        #pragma unroll
        for (int mi = 0; mi < 4; mi++)
            #pragma unroll
            for (int ni = 0; ni < 4; ni++)
                acc[mi][ni] = __builtin_amdgcn_mfma_f32_16x16x32_bf16(
                                  af[mi], bfr[ni], acc[mi][ni], 0, 0, 0);
    }
    asum += __shfl_xor(asum, 1);  asum += __shfl_xor(asum, 2);
    vdot += __shfl_xor(vdot, 1);  vdot += __shfl_xor(vdot, 2);
    if (akq == 0) {
        wmask[m0 + arow] = (asum != 0.0f) ? 1 : 0;
        dvec[m0 + arow] = vdot;
    }
    #pragma unroll
    for (int ni = 0; ni < 4; ni++) {
        const int col = wn + ni * 16 + (lane & 15);
        #pragma unroll
        for (int mi = 0; mi < 4; mi++) {
            const int row = m0 + wm + mi * 16 + ((lane >> 4) << 2);
            #pragma unroll
            for (int r = 0; r < 4; r++)
                G[(long)(row + r) * NH + col] = f2bf(acc[mi][ni][r]);
        }
    }
}

// ---------------------------------------------------------------------------
// gru_scan (R17 form, measured 233 us): i8-MFMA recurrence. 256 blocks x
// 1024 threads (16 waves); wave owns 16 h-cols; wf = 48 VGPR i8 frags;
// mfma_i32_16x16x64_i8 K=64. W scale 400, h scale 127; f32 h master in regs.
// ---------------------------------------------------------------------------
__global__ __launch_bounds__(1024)
__attribute__((amdgpu_waves_per_eu(4, 4)))
void gru_scan(const unsigned short* __restrict__ xg,   // [51200][768] bf16 (incl biasC)
              const float* __restrict__ Whh,            // [768][256] fp32
              const float* __restrict__ bhh,            // [768]
              const int* __restrict__ lengths,          // [256]
              unsigned short* __restrict__ hout) {      // [51200][256] bf16 (masked)
    __shared__ __align__(16) unsigned char h8[2][256];  // int8 h double buffer
    const int tid = threadIdx.x;
    const int lane = tid & 63;
    const int wave = tid >> 6;               // 0..15
    const int b = blockIdx.x;
    const int l = lane & 15;
    const int sub = lane >> 4;               // k-subslice 0..3
    const int c = wave * 16 + l;             // this lane's h-col

    // resident W_hh i8 B-frags: gate g, ktile kt: byte j <- W[g*256+c][kt*64+sub*16+j]
    i32x4 wf[3][4];
    #pragma unroll
    for (int g = 0; g < 3; g++) {
        const float* wr = Whh + (long)(g * 256 + c) * NH;
        #pragma unroll
        for (int kt = 0; kt < 4; kt++) {
            const float* s = wr + kt * 64 + sub * 16;
            i32x4 v;
            #pragma unroll
            for (int q = 0; q < 4; q++) {
                unsigned pack = 0;
                #pragma unroll
                for (int j = 0; j < 4; j++) {
                    int wq = (int)rintf(s[q * 4 + j] * 400.0f);
                    wq = wq > 127 ? 127 : (wq < -127 ? -127 : wq);
                    pack |= ((unsigned)(wq & 0xff)) << (8 * j);
                }
                v[q] = (int)pack;
            }
            wf[g][kt] = v;
        }
    }
    const float bhn = bhh[512 + c];          // n-gate b_hh (r,z folded into xg)
    const int len = lengths[b];
    if (tid < 128) ((unsigned*)h8)[tid] = 0u;   // zero both h buffers (512 B)

    const unsigned short* xrow = xg + (long)b * NT * G3H;
    const bool gl = (lane < 16);
    unsigned short xv0 = 0, xv1 = 0, xv2 = 0;
    if (gl) { xv0 = xrow[c]; xv1 = xrow[256 + c]; xv2 = xrow[512 + c]; }
    float hp = 0.0f;
    const float ISC = 1.0f / (400.0f * 127.0f);

    asm volatile("s_waitcnt lgkmcnt(0)" ::: "memory");
    __builtin_amdgcn_sched_barrier(0);
    __builtin_amdgcn_s_barrier();
    __builtin_amdgcn_sched_barrier(0);

    for (int t = 0; t < NT; t++) {
        // hg = h_{t-1} @ Whh^T for this wave's 16 cols x 3 gates (i8, K=64)
        const unsigned char* hb = h8[(t + 1) & 1];
        i32x4 a0 = {}, a1 = {}, a2 = {};
        #pragma unroll
        for (int kt = 0; kt < 4; kt++) {
            const i32x4 af = *(const i32x4*)(hb + kt * 64 + (sub << 4));
            a0 = __builtin_amdgcn_mfma_i32_16x16x64_i8(af, wf[0][kt], a0, 0, 0, 0);
            a1 = __builtin_amdgcn_mfma_i32_16x16x64_i8(af, wf[1][kt], a1, 0, 0, 0);
            a2 = __builtin_amdgcn_mfma_i32_16x16x64_i8(af, wf[2][kt], a2, 0, 0, 0);
        }
        if (gl) {
            const float r = sigm(bf2f(xv0) + (float)a0[0] * ISC);
            const float z = sigm(bf2f(xv1) + (float)a1[0] * ISC);
            const float n = tanh_fast(bf2f(xv2) + r * ((float)a2[0] * ISC + bhn));
            hp = (1.0f - z) * n + z * hp;
            h8[t & 1][c] = (unsigned char)((int)rintf(hp * 127.0f) & 0xff);
            hout[((long)b * NT + t) * NH + c] = (t < len) ? f2bf(hp) : (unsigned short)0;
            if (t + 1 < NT) {                 // prefetch next step's xg (floats past barrier)
                const unsigned short* xn = xrow + (long)(t + 1) * G3H;
                xv0 = xn[c]; xv1 = xn[256 + c]; xv2 = xn[512 + c];
            }
        }
        // LDS-only baton: no vmcnt drain (hout stores + xg prefetch stay in flight)
        asm volatile("s_waitcnt lgkmcnt(0)" ::: "memory");
        __builtin_amdgcn_sched_barrier(0);
        __builtin_amdgcn_s_barrier();
        __builtin_amdgcn_sched_barrier(0);
    }
}

// ---------------------------------------------------------------------------
// logits_dur: wave per (b,t) row; only |w-fix|<=8 dots computed; dur fused.
// ---------------------------------------------------------------------------
__global__ __launch_bounds__(256)
void logits_dur(const unsigned short* __restrict__ Hrow,   // hout [51200][256]
                const unsigned short* __restrict__ G,      // [51200][256]
                const int* __restrict__ fix_seq,           // [51200]
                const unsigned char* __restrict__ wmask,   // [51200]
                const float* __restrict__ dvec,            // [51200]
                const float* __restrict__ Wdur, const float* __restrict__ bdur,
                float* __restrict__ out) {
    __shared__ float dots[4][20];
    const int wv = threadIdx.x >> 6;
    const int gwave = (int)blockIdx.x * 4 + wv;            // 0..51199 = b*200+t
    const int lane = threadIdx.x & 63;
    const int l16 = lane & 15;
    const int grp = lane >> 4;                              // 0..3
    const int b = gwave / NT;

    const unsigned short* hp = Hrow + (long)gwave * NH + l16 * 16;
    const bf16x8 h0 = *(const bf16x8*)hp;
    const bf16x8 h1 = *(const bf16x8*)(hp + 8);
    float hf[16];
    #pragma unroll
    for (int j = 0; j < 8; j++) { hf[j] = bf2f((unsigned short)h0[j]);
                                  hf[8 + j] = bf2f((unsigned short)h1[j]); }

    const int fix = fix_seq[gwave];
    const int wbase = fix - 8;

    if (fix != 0) {
        #pragma unroll
        for (int it = 0; it < 5; it++) {
            const int wi = it * 4 + grp;                    // 0..19 (17..19 unused)
            int w = wbase + wi;
            w = w < 0 ? 0 : (w > NW - 1 ? NW - 1 : w);      // clamp for safe load
            const unsigned short* gp = G + ((long)b * NW + w) * NH + l16 * 16;
            const bf16x8 g0 = *(const bf16x8*)gp;
            const bf16x8 g1 = *(const bf16x8*)(gp + 8);
            float p = 0.0f;
            #pragma unroll
            for (int j = 0; j < 8; j++) {
                p += hf[j] * bf2f((unsigned short)g0[j]);
                p += hf[8 + j] * bf2f((unsigned short)g1[j]);
            }
            p += __shfl_xor(p, 1); p += __shfl_xor(p, 2);
            p += __shfl_xor(p, 4); p += __shfl_xor(p, 8);
            if (l16 == 0 && wi < 17) dots[wv][wi] = p;
        }
    }
    float pd = 0.0f;
    #pragma unroll
    for (int j = 0; j < 16; j++) pd += hf[j] * Wdur[l16 * 16 + j];
    pd += __shfl_xor(pd, 1); pd += __shfl_xor(pd, 2);
    pd += __shfl_xor(pd, 4); pd += __shfl_xor(pd, 8);
    if (lane == 0) out[(long)NB * NT * NW + gwave] = pd + bdur[0];

    __syncthreads();

    if (lane < 50) {
        float4 o;
        #pragma unroll
        for (int c = 0; c < 4; c++) {
            const int w = lane * 4 + c;
            const int wi = w - wbase;
            const int wic = wi < 0 ? 0 : (wi > 16 ? 16 : wi);
            const bool ok = (fix != 0) && ((unsigned)wi < 17u) && (wmask[b * NW + w] != 0);
            const float val = dots[wv][wic] + dvec[b * NW + w];
            ((float*)&o)[c] = ok ? val : -1e9f;
        }
        *(float4*)(out + (long)gwave * NW + lane * 4) = o;
    }
}

// ---------------------------------------------------------------------------
extern "C" void kernel_launch(void* const* d_in, const int* in_sizes, int n_in,
                              void* d_out, int out_size, void* d_ws, size_t ws_size,
                              hipStream_t stream) {
    (void)in_sizes; (void)n_in; (void)out_size; (void)ws_size;
    const float* inputs  = (const float*)d_in[0];
    const int*   fix_seq = (const int*)d_in[1];
    const float* fwe     = (const float*)d_in[2];
    const int*   lengths = (const int*)d_in[3];
    const float* emb     = (const float*)d_in[5];
    const float* Wih     = (const float*)d_in[6];
    const float* bih     = (const float*)d_in[7];
    const float* Whh     = (const float*)d_in[8];
    const float* bhh     = (const float*)d_in[9];
    const float* Wout    = (const float*)d_in[10];
    const float* bout    = (const float*)d_in[11];
    const float* Wdur    = (const float*)d_in[12];
    const float* bdur    = (const float*)d_in[13];
    float* out = (float*)d_out;

    char* ws = (char*)d_ws;
    // region layout (bytes, all 256-aligned):
    //   R0 [0, 81,920,000)            A_bf16 [51200][800]  -> G [51200][256] after gemm1
    //   R1 [81,920,000, +78,643,200)  xg_bf16 [51200][768]
    //   R2 [160,563,200, +26,214,400) hout_bf16 [51200][256]
    //   [186,777,600, +1,228,800)     W_ih bf16
    //   [188,006,400, +393,216)       W_outT bf16 [256][768]
    //   [188,399,616, +51,200)        word_mask u8
    //   [188,450,816, +3,072)         biasC f32 [768]
    //   [188,453,888, +204,800)       dvec f32 [51200]
    unsigned short* Abf     = (unsigned short*)(ws);
    unsigned short* xgbf    = (unsigned short*)(ws + 81920000);
    unsigned short* hout    = (unsigned short*)(ws + 160563200);
    unsigned short* Wihbf   = (unsigned short*)(ws + 186777600);
    unsigned short* WoutTbf = (unsigned short*)(ws + 188006400);
    unsigned char*  wmask   = (unsigned char*)(ws + 188399616);
    float*          biasC   = (float*)(ws + 188450816);
    float*          dvec    = (float*)(ws + 188453888);
    unsigned short* Gbf     = Abf;    // R0: A dead after gemm1

    prep1<<<2048, 256, 0, stream>>>(inputs, fix_seq, emb, Wih, Wout, bih, bhh,
                                    Abf, Wihbf, WoutTbf, biasC);
    gemm_bt128<<<400 * 3, 512, 0, stream>>>(Abf, Wihbf, biasC, xgbf, MROWS, G3H, KIN);
    gemmG_f32<<<400, 512, 0, stream>>>(fwe, WoutTbf, bout, Gbf, wmask, dvec);
    gru_scan<<<256, 1024, 0, stream>>>(xgbf, Whh, bhh, lengths, hout);
    logits_dur<<<12800, 256, 0, stream>>>(hout, Gbf, fix_seq, wmask, dvec, Wdur, bdur, out);
}